// Round 1
// baseline (410.051 us; speedup 1.0000x reference)
//
#include <hip/hip_runtime.h>
#include <cstddef>

constexpr int N0 = 16384, N1 = 4096, N2 = 1024, N3 = 256;
constexpr int E0 = 6 * N0, E1 = 6 * N1, E2 = 6 * N2, E3 = 6 * N3;
constexpr int LOCN = 32 * N0; // 524288

// workspace layout (float offsets)
constexpr size_t OFF_XLZ  = 0;                    // 128
constexpr size_t OFF_STAT = 128;                  // 6*64 stats (sum | sumsq)
constexpr size_t OFF_XGF  = 512;                  // 16384*3
constexpr size_t OFF_X    = 49664;                // 16384*32
constexpr size_t OFF_Y    = OFF_X   + 524288;
constexpr size_t OFF_ACC  = OFF_Y   + 524288;
constexpr size_t OFF_ICNT = OFF_ACC + 524288;     // 16384
constexpr size_t OFF_XW   = OFF_ICNT + 16384;     // up to 1024*32

// x = z @ lin_w + lin_b ; xlz = x[32:160] ; xw0 = broadcast64( x[:32] @ Wg[0] )
// also zeroes all BN stats slots for this call.
__global__ void k_lin(const float* __restrict__ z, const float* __restrict__ lin_w,
                      const float* __restrict__ lin_b, const float* __restrict__ Wg0,
                      float* __restrict__ xlz, float* __restrict__ xw0,
                      float* __restrict__ stats) {
    __shared__ float zl[128];
    __shared__ float xl[160];
    __shared__ float xwl[32];
    int t = threadIdx.x;
    for (int i = t; i < 6 * 64; i += 256) stats[i] = 0.f;
    if (t < 128) zl[t] = z[t];
    __syncthreads();
    if (t < 160) {
        float s = lin_b[t];
        for (int k = 0; k < 128; k++) s += zl[k] * lin_w[k * 160 + t];
        xl[t] = s;
    }
    __syncthreads();
    if (t < 128) xlz[t] = xl[32 + t];
    if (t < 32) {
        float s = 0.f;
        for (int k = 0; k < 32; k++) s += xl[k] * Wg0[k * 32 + t];
        xwl[t] = s;
    }
    __syncthreads();
    for (int i = t; i < 64 * 32; i += 256) xw0[i] = xwl[i & 31];
}

// xl0 = xlz @ loc_w + loc_b  (128 x 524288 streaming matvec), float4-coalesced
__global__ void k_matvec(const float* __restrict__ xlz, const float* __restrict__ loc_w,
                         const float* __restrict__ loc_b, float* __restrict__ out) {
    __shared__ float xs[128];
    int t = threadIdx.x;
    if (t < 128) xs[t] = xlz[t];
    __syncthreads();
    int j0 = (blockIdx.x * 256 + t) * 4;
    float4 acc = *(const float4*)(loc_b + j0);
#pragma unroll 4
    for (int k = 0; k < 128; k++) {
        float xk = xs[k];
        float4 w = *(const float4*)(loc_w + (size_t)k * LOCN + j0);
        acc.x += xk * w.x; acc.y += xk * w.y; acc.z += xk * w.z; acc.w += xk * w.w;
    }
    *(float4*)(out + j0) = acc;
}

// y = U(n x m) @ xw(m x 32); epilogue: acc = y, icnt = 1 (self-loop init).
// 32 rows per block, K-chunks of 64 staged in LDS.
__global__ void k_gemmU32(const float* __restrict__ U, const float* __restrict__ xw, int m,
                          float* __restrict__ y, float* __restrict__ acc,
                          float* __restrict__ icnt) {
    __shared__ float ut[32 * 64];
    __shared__ float xt[64 * 32];
    int t = threadIdx.x;
    int r0 = blockIdx.x * 32;
    int f = t & 31, rg = t >> 5;
    float a0 = 0, a1 = 0, a2 = 0, a3 = 0;
    for (int k0 = 0; k0 < m; k0 += 64) {
        {
            int row = t >> 3, c0 = (t & 7) * 8;
            const float* src = U + (size_t)(r0 + row) * m + k0 + c0;
            float4 u1 = *(const float4*)src, u2 = *(const float4*)(src + 4);
            float* d = ut + row * 64 + c0;
            *(float4*)d = u1; *(float4*)(d + 4) = u2;
        }
        {
            const float* src = xw + (size_t)k0 * 32 + t * 8;
            float4 u1 = *(const float4*)src, u2 = *(const float4*)(src + 4);
            float* d = xt + t * 8;
            *(float4*)d = u1; *(float4*)(d + 4) = u2;
        }
        __syncthreads();
#pragma unroll
        for (int kk = 0; kk < 64; kk++) {
            float xv = xt[kk * 32 + f];
            a0 += ut[(rg     ) * 64 + kk] * xv;
            a1 += ut[(rg +  8) * 64 + kk] * xv;
            a2 += ut[(rg + 16) * 64 + kk] * xv;
            a3 += ut[(rg + 24) * 64 + kk] * xv;
        }
        __syncthreads();
    }
    int b = (r0 + rg) * 32 + f;
    y[b] = a0;            acc[b] = a0;
    y[b + 8 * 32]  = a1;  acc[b + 8 * 32]  = a1;
    y[b + 16 * 32] = a2;  acc[b + 16 * 32] = a2;
    y[b + 24 * 32] = a3;  acc[b + 24 * 32] = a3;
    if (t < 32) icnt[r0 + t] = 1.f;
}

// y = U0(16384 x 4096) @ xw3(4096 x 3); wave-per-row, xw3 in LDS with
// perm k -> (k&3)*1024 + (k>>2) so stride-4 lane reads are conflict-free.
__global__ void k_gemmU3(const float* __restrict__ U0, const float* __restrict__ xw3,
                         float* __restrict__ y, float* __restrict__ acc,
                         float* __restrict__ icnt) {
    __shared__ float pl[3 * 4096];
    int t = threadIdx.x;
    for (int i = t; i < 12288; i += 256) {
        int k = i / 3, h = i - 3 * k;
        pl[h * 4096 + ((k & 3) << 10) + (k >> 2)] = xw3[i];
    }
    __syncthreads();
    int w = t >> 6, lane = t & 63;
    for (int rr = 0; rr < 4; rr++) {
        int row = blockIdx.x * 16 + w * 4 + rr;
        const float4* up = (const float4*)(U0 + (size_t)row * 4096);
        float a0 = 0, a1 = 0, a2 = 0;
#pragma unroll 4
        for (int c = 0; c < 16; c++) {
            float4 u = up[c * 64 + lane];
            int b = c * 64 + lane;
            a0 += u.x * pl[b]          + u.y * pl[1024 + b]        + u.z * pl[2048 + b]        + u.w * pl[3072 + b];
            a1 += u.x * pl[4096 + b]   + u.y * pl[5120 + b]        + u.z * pl[6144 + b]        + u.w * pl[7168 + b];
            a2 += u.x * pl[8192 + b]   + u.y * pl[9216 + b]        + u.z * pl[10240 + b]       + u.w * pl[11264 + b];
        }
        for (int o = 32; o; o >>= 1) {
            a0 += __shfl_down(a0, o, 64);
            a1 += __shfl_down(a1, o, 64);
            a2 += __shfl_down(a2, o, 64);
        }
        if (lane == 0) {
            y[row * 3] = a0; y[row * 3 + 1] = a1; y[row * 3 + 2] = a2;
            acc[row * 3] = a0; acc[row * 3 + 1] = a1; acc[row * 3 + 2] = a2;
            icnt[row] = 1.f;
        }
    }
}

// edge scatter, F=32: acc[dst] += y[src]; icnt[dst] += 1
__global__ void k_edges32(const int* __restrict__ A, int E, const float* __restrict__ y,
                          float* __restrict__ acc, float* __restrict__ icnt) {
    int t = blockIdx.x * 256 + threadIdx.x;
    int e = t >> 5, f = t & 31;
    if (e >= E) return;
    int s = A[e], d = A[E + e];
    atomicAdd(acc + (size_t)d * 32 + f, y[(size_t)s * 32 + f]);
    if (f == 0) atomicAdd(icnt + d, 1.f);
}

// edge scatter, F=3
__global__ void k_edges3(const int* __restrict__ A, int E, const float* __restrict__ y,
                         float* __restrict__ acc, float* __restrict__ icnt) {
    int t = blockIdx.x * 256 + threadIdx.x;
    int e = t >> 2, r = t & 3;
    if (e >= E) return;
    int s = A[e], d = A[E + e];
    if (r < 3) atomicAdd(acc + (size_t)d * 3 + r, y[(size_t)s * 3 + r]);
    else       atomicAdd(icnt + d, 1.f);
}

// feast finalize (F=32): x = acc/icnt + bias; accumulate per-feature sum/sumsq
// into stats via block pre-reduction (grid fixed at 256 blocks).
__global__ void k_fin_bn(const float* __restrict__ acc, const float* __restrict__ icnt,
                         const float* __restrict__ bias, int n, float* __restrict__ xout,
                         float* __restrict__ stats) {
    __shared__ float red[256], red2[256];
    int t = threadIdx.x;
    int f = t & 31, nl = t >> 5;
    int npb = n >> 8;
    int base = blockIdx.x * npb;
    float s = 0.f, ss = 0.f;
    for (int idx = nl; idx < npb; idx += 8) {
        int node = base + idx;
        float v = acc[(size_t)node * 32 + f] / icnt[node] + bias[f];
        xout[(size_t)node * 32 + f] = v;
        s += v; ss += v * v;
    }
    red[t] = s; red2[t] = ss;
    __syncthreads();
    if (t < 32) {
        float a = 0.f, b = 0.f;
        for (int j = 0; j < 8; j++) { a += red[t + 32 * j]; b += red2[t + 32 * j]; }
        atomicAdd(stats + t, a);
        atomicAdd(stats + 32 + t, b);
    }
}

// per-node: optional BN(+leakyReLU) on 32-wide row, then row @ W (32 x FO).
// mode 0: write xw only. mode 1: write y + acc(=y) + icnt(=1) (self-loop init).
template <int FO>
__global__ void __launch_bounds__(64) k_bnxw(const float* __restrict__ xin,
                                             const float* __restrict__ stats,
                                             const float* __restrict__ gam,
                                             const float* __restrict__ bet,
                                             const float* __restrict__ W,
                                             int do_bn, float invn, int mode,
                                             float* __restrict__ out_y,
                                             float* __restrict__ out_acc,
                                             float* __restrict__ icnt) {
    __shared__ float Wl[32 * FO];
    __shared__ float sc[32], sh[32];
    int t = threadIdx.x;
    for (int i = t; i < 32 * FO; i += 64) Wl[i] = W[i];
    if (t < 32) {
        if (do_bn) {
            float mu  = stats[t] * invn;
            float var = stats[32 + t] * invn - mu * mu;
            float rs  = rsqrtf(var + 1e-5f);
            float scv = rs * gam[t];
            sc[t] = scv; sh[t] = bet[t] - mu * scv;
        } else { sc[t] = 1.f; sh[t] = 0.f; }
    }
    __syncthreads();
    int node = blockIdx.x * 64 + t;
    float x[32];
    const float4* xp = (const float4*)(xin + (size_t)node * 32);
#pragma unroll
    for (int j = 0; j < 8; j++) {
        float4 v = xp[j];
        x[4 * j] = v.x; x[4 * j + 1] = v.y; x[4 * j + 2] = v.z; x[4 * j + 3] = v.w;
    }
    if (do_bn) {
#pragma unroll
        for (int k = 0; k < 32; k++) {
            float v = sc[k] * x[k] + sh[k];
            x[k] = v > 0.f ? v : 0.01f * v;
        }
    }
    float yv[FO];
#pragma unroll
    for (int q = 0; q < FO; q++) {
        float s = 0.f;
#pragma unroll
        for (int k = 0; k < 32; k++) s += x[k] * Wl[k * FO + q];
        yv[q] = s;
    }
    float* yp = out_y + (size_t)node * FO;
#pragma unroll
    for (int q = 0; q < FO; q++) yp[q] = yv[q];
    if (mode == 1) {
        float* ap = out_acc + (size_t)node * FO;
#pragma unroll
        for (int q = 0; q < FO; q++) ap[q] = yv[q];
        icnt[node] = 1.f;
    }
}

// global-path final feast output: xgf = acc/icnt + bg3
__global__ void k_fin_g(const float* __restrict__ acc, const float* __restrict__ icnt,
                        const float* __restrict__ b3, float* __restrict__ xgf) {
    int i = blockIdx.x * 256 + threadIdx.x;
    if (i >= N0 * 3) return;
    int node = i / 3, h = i - node * 3;
    xgf[i] = acc[i] / icnt[node] + b3[h];
}

// local-path final + combine: out = 0.01*xgf + 0.99*(acc/icnt + bl3)
__global__ void k_fin_l(const float* __restrict__ acc, const float* __restrict__ icnt,
                        const float* __restrict__ b3, const float* __restrict__ xgf,
                        float* __restrict__ out) {
    int i = blockIdx.x * 256 + threadIdx.x;
    if (i >= N0 * 3) return;
    int node = i / 3, h = i - node * 3;
    out[i] = 0.01f * xgf[i] + 0.99f * (acc[i] / icnt[node] + b3[h]);
}

extern "C" void kernel_launch(void* const* d_in, const int* in_sizes, int n_in,
                              void* d_out, int out_size, void* d_ws, size_t ws_size,
                              hipStream_t stream) {
    const float* z     = (const float*)d_in[0];
    const float* lin_w = (const float*)d_in[1];
    const float* lin_b = (const float*)d_in[2];
    const float* loc_w = (const float*)d_in[3];
    const float* loc_b = (const float*)d_in[4];
    const float* Wg    = (const float*)d_in[5];
    const float* bg    = (const float*)d_in[8];
    const float* Wg3   = (const float*)d_in[9];
    const float* bg3   = (const float*)d_in[12];
    const float* Wl    = (const float*)d_in[13];
    const float* bl    = (const float*)d_in[16];
    const float* Wl3   = (const float*)d_in[17];
    const float* bl3   = (const float*)d_in[20];
    const float* gam_g = (const float*)d_in[21];
    const float* bet_g = (const float*)d_in[22];
    const float* gam_l = (const float*)d_in[23];
    const float* bet_l = (const float*)d_in[24];
    const float* U0    = (const float*)d_in[25];
    const float* U1    = (const float*)d_in[26];
    const float* U2    = (const float*)d_in[27];
    const float* U3    = (const float*)d_in[28];
    const int* A0 = (const int*)d_in[29];
    const int* A1 = (const int*)d_in[30];
    const int* A2 = (const int*)d_in[31];
    const int* A3 = (const int*)d_in[32];

    float* ws    = (float*)d_ws;
    float* xlz   = ws + OFF_XLZ;
    float* stats = ws + OFF_STAT;
    float* xgf   = ws + OFF_XGF;
    float* bx    = ws + OFF_X;
    float* by    = ws + OFF_Y;
    float* ba    = ws + OFF_ACC;
    float* ic    = ws + OFF_ICNT;
    float* bxw   = ws + OFF_XW;
    float* out   = (float*)d_out;

    // linear head (also zeroes BN stats)
    k_lin<<<1, 256, 0, stream>>>(z, lin_w, lin_b, Wg, xlz, bxw, stats);

    // ---- global path ----
    // layer 0: U3 (256x64)
    k_gemmU32<<<N3 / 32, 256, 0, stream>>>(U3, bxw, 64, by, ba, ic);
    k_edges32<<<(E3 * 32) / 256, 256, 0, stream>>>(A3, E3, by, ba, ic);
    k_fin_bn<<<256, 256, 0, stream>>>(ba, ic, bg, N3, bx, stats);
    k_bnxw<32><<<N3 / 64, 64, 0, stream>>>(bx, stats, gam_g, bet_g, Wg + 1024,
                                           1, 1.f / N3, 0, bxw, nullptr, nullptr);
    // layer 1: U2 (1024x256)
    k_gemmU32<<<N2 / 32, 256, 0, stream>>>(U2, bxw, 256, by, ba, ic);
    k_edges32<<<(E2 * 32) / 256, 256, 0, stream>>>(A2, E2, by, ba, ic);
    k_fin_bn<<<256, 256, 0, stream>>>(ba, ic, bg + 32, N2, bx, stats + 64);
    k_bnxw<32><<<N2 / 64, 64, 0, stream>>>(bx, stats + 64, gam_g + 32, bet_g + 32, Wg + 2048,
                                           1, 1.f / N2, 0, bxw, nullptr, nullptr);
    // layer 2: U1 (4096x1024)
    k_gemmU32<<<N1 / 32, 256, 0, stream>>>(U1, bxw, 1024, by, ba, ic);
    k_edges32<<<(E1 * 32) / 256, 256, 0, stream>>>(A1, E1, by, ba, ic);
    k_fin_bn<<<256, 256, 0, stream>>>(ba, ic, bg + 64, N1, bx, stats + 128);
    k_bnxw<3><<<N1 / 64, 64, 0, stream>>>(bx, stats + 128, gam_g + 64, bet_g + 64, Wg3,
                                          1, 1.f / N1, 0, bxw, nullptr, nullptr);
    // layer 3: U0 (16384x4096), F=3
    k_gemmU3<<<1024, 256, 0, stream>>>(U0, bxw, by, ba, ic);
    k_edges3<<<(E0 * 4) / 256, 256, 0, stream>>>(A0, E0, by, ba, ic);
    k_fin_g<<<(N0 * 3 + 255) / 256, 256, 0, stream>>>(ba, ic, bg3, xgf);

    // ---- local path ----
    k_matvec<<<LOCN / 1024, 256, 0, stream>>>(xlz, loc_w, loc_b, bx);
    k_bnxw<32><<<N0 / 64, 64, 0, stream>>>(bx, nullptr, nullptr, nullptr, Wl,
                                           0, 0.f, 1, by, ba, ic);
    k_edges32<<<(E0 * 32) / 256, 256, 0, stream>>>(A0, E0, by, ba, ic);
    k_fin_bn<<<256, 256, 0, stream>>>(ba, ic, bl, N0, bx, stats + 192);
    k_bnxw<32><<<N0 / 64, 64, 0, stream>>>(bx, stats + 192, gam_l, bet_l, Wl + 1024,
                                           1, 1.f / N0, 1, by, ba, ic);
    k_edges32<<<(E0 * 32) / 256, 256, 0, stream>>>(A0, E0, by, ba, ic);
    k_fin_bn<<<256, 256, 0, stream>>>(ba, ic, bl + 32, N0, bx, stats + 256);
    k_bnxw<32><<<N0 / 64, 64, 0, stream>>>(bx, stats + 256, gam_l + 32, bet_l + 32, Wl + 2048,
                                           1, 1.f / N0, 1, by, ba, ic);
    k_edges32<<<(E0 * 32) / 256, 256, 0, stream>>>(A0, E0, by, ba, ic);
    k_fin_bn<<<256, 256, 0, stream>>>(ba, ic, bl + 64, N0, bx, stats + 320);
    k_bnxw<3><<<N0 / 64, 64, 0, stream>>>(bx, stats + 320, gam_l + 64, bet_l + 64, Wl3,
                                          1, 1.f / N0, 1, by, ba, ic);
    k_edges3<<<(E0 * 4) / 256, 256, 0, stream>>>(A0, E0, by, ba, ic);
    k_fin_l<<<(N0 * 3 + 255) / 256, 256, 0, stream>>>(ba, ic, bl3, xgf, out);
}